// Round 8
// baseline (532.583 us; speedup 1.0000x reference)
//
#include <hip/hip_runtime.h>
#include <hip/hip_bf16.h>

#define NN 60000
#define NE 600000
#define DD 128
#define NTOT (NE + NN)
#define NB ((NN + 255) / 256)   // 235 blocks for scan

typedef __attribute__((ext_vector_type(8))) short short8;
typedef __attribute__((ext_vector_type(4))) float f32x4;

__device__ __forceinline__ unsigned short f2bf(float f) {
    unsigned int u = __float_as_uint(f);
    unsigned int r = (u + 0x7FFF + ((u >> 16) & 1)) >> 16;  // RNE
    return (unsigned short)r;
}
__device__ __forceinline__ float bflo(unsigned int u) { return __uint_as_float(u << 16); }
__device__ __forceinline__ float bfhi(unsigned int u) { return __uint_as_float(u & 0xFFFF0000u); }

// ---- degree (edges only; +1 self-loop folded in later) ----
__global__ __launch_bounds__(256) void deg_kernel(const int* __restrict__ dst, int* __restrict__ deg) {
    int e = blockIdx.x * 256 + threadIdx.x;
    if (e < NE) atomicAdd(&deg[dst[e]], 1);
}

// ---- scanA: per-block sums of (deg+1), fused dinv ----
__global__ __launch_bounds__(256) void scanA_kernel(const int* __restrict__ deg, int* __restrict__ partials,
                                                    float* __restrict__ dinv) {
    __shared__ int lds[256];
    int i = blockIdx.x * 256 + threadIdx.x;
    int dv = (i < NN) ? deg[i] : 0;
    if (i < NN) dinv[i] = rsqrtf((float)(dv + 1));
    int v = (i < NN) ? dv + 1 : 0;
    lds[threadIdx.x] = v;
    __syncthreads();
    for (int off = 128; off > 0; off >>= 1) {
        if (threadIdx.x < off) lds[threadIdx.x] += lds[threadIdx.x + off];
        __syncthreads();
    }
    if (threadIdx.x == 0) partials[blockIdx.x] = lds[0];
}

__global__ __launch_bounds__(256) void scanB_kernel(const int* __restrict__ partials,
                                                    int* __restrict__ blockoff,
                                                    int* __restrict__ rowptr) {
    __shared__ int lds[256];
    int t = threadIdx.x;
    int v = (t < NB) ? partials[t] : 0;
    lds[t] = v;
    __syncthreads();
    for (int off = 1; off < 256; off <<= 1) {
        int u = (t >= off) ? lds[t - off] : 0;
        __syncthreads();
        lds[t] += u;
        __syncthreads();
    }
    if (t < NB) blockoff[t] = lds[t] - v;  // exclusive
    if (t == 0) rowptr[NN] = NTOT;
}

__global__ __launch_bounds__(256) void scanC_kernel(const int* __restrict__ deg,
                                                    const int* __restrict__ blockoff,
                                                    int* __restrict__ rowptr) {
    __shared__ int lds[256];
    int i = blockIdx.x * 256 + threadIdx.x;
    int t = threadIdx.x;
    int v = (i < NN) ? deg[i] + 1 : 0;
    lds[t] = v;
    __syncthreads();
    for (int off = 1; off < 256; off <<= 1) {
        int u = (t >= off) ? lds[t - off] : 0;
        __syncthreads();
        lds[t] += u;
        __syncthreads();
    }
    if (i < NN) rowptr[i] = blockoff[blockIdx.x] + lds[t] - v;
}

// ---- CSR fill: packed int2{src, coef_bits} -> ONE 8B scattered store per edge ----
__global__ __launch_bounds__(256) void fill_kernel(const int* __restrict__ src, const int* __restrict__ dst,
                                                   const int* __restrict__ rowptr, int* __restrict__ cursor,
                                                   const float* __restrict__ dinv,
                                                   int2* __restrict__ csr) {
    int e = blockIdx.x * 256 + threadIdx.x;
    if (e >= NTOT) return;
    int s, t;
    if (e < NE) { s = src[e]; t = dst[e]; }
    else { s = t = e - NE; }
    int pos = atomicAdd(&cursor[t], 1);
    int2 rec;
    rec.x = s;
    rec.y = __float_as_int(dinv[s] * dinv[t]);
    csr[rowptr[t] + pos] = rec;
}

// ---- W convert+transpose, all 3 layers: Wt[L][n][k] bf16 <- W_L[k][n] fp32 ----
__global__ __launch_bounds__(256) void wcvt_kernel(const float* __restrict__ W0, const float* __restrict__ W1,
                                                   const float* __restrict__ W2, unsigned short* __restrict__ Wt) {
    int idx = blockIdx.x * 256 + threadIdx.x;  // 3*64*128 items
    if (idx >= 3 * 64 * DD) return;
    int L = idx / (64 * DD);
    int r = idx - L * 64 * DD;
    const float* W = (L == 0) ? W0 : (L == 1) ? W1 : W2;
    int k2 = (r >> 7) * 2;
    int n = r & 127;
    unsigned int b0 = f2bf(W[k2 * DD + n]);
    unsigned int b1 = f2bf(W[(k2 + 1) * DD + n]);
    ((unsigned int*)Wt)[(L * DD * DD + n * DD + k2) >> 1] = b0 | (b1 << 16);
}

// ---- MFMA GEMM: C_bf16[NN x 128] = f(A) @ W ----
// BF16IN: A is bf16 (layers 1,2; normp applied); else fp32 (layer 0, normp null).
// One wave per 16 rows; 8 col-tiles of 16; K=128 in 4 chunks of 32.
// Layouts (m89/m120): A/B frag own=lane&15,k=(lane>>4)*8+j; C/D col=lane&15,row=(lane>>4)*4+reg.
// NOTE: no waves/EU hint — (256,4) caused 64-VGPR cap + acc spill (R3: 1 GiB traffic).
template <bool BF16IN>
__global__ __launch_bounds__(256) void gemm_mfma_kernel(const void* __restrict__ Ain,
                                                        const unsigned short* __restrict__ Wt,
                                                        const float* __restrict__ normp,
                                                        unsigned short* __restrict__ C) {
    __shared__ float lds[4][16][132];  // 33 KB, per-wave repack tiles
    int tid = threadIdx.x;
    int wslot = tid >> 6;
    int wrow0 = (blockIdx.x * 4 + wslot) * 16;
    if (wrow0 >= NN) return;
    int l = tid & 63;
    int m = l & 15;
    int q = l >> 4;

    f32x4 acc[8];
#pragma unroll
    for (int i = 0; i < 8; i++) acc[i] = (f32x4){0.f, 0.f, 0.f, 0.f};

#pragma unroll
    for (int kc = 0; kc < 4; kc++) {
        int k0 = kc * 32 + q * 8;
        float a[8];
        if (BF16IN) {
            const unsigned short* arow = (const unsigned short*)Ain + (size_t)(wrow0 + m) * DD;
            uint4 u = *(const uint4*)(arow + k0);
            a[0] = bflo(u.x); a[1] = bfhi(u.x); a[2] = bflo(u.y); a[3] = bfhi(u.y);
            a[4] = bflo(u.z); a[5] = bfhi(u.z); a[6] = bflo(u.w); a[7] = bfhi(u.w);
        } else {
            const float* arow = (const float*)Ain + (size_t)(wrow0 + m) * DD;
            float4 a0 = *(const float4*)(arow + k0);
            float4 a1 = *(const float4*)(arow + k0 + 4);
            a[0] = a0.x; a[1] = a0.y; a[2] = a0.z; a[3] = a0.w;
            a[4] = a1.x; a[5] = a1.y; a[6] = a1.z; a[7] = a1.w;
        }
        if (normp) {
#pragma unroll
            for (int j = 0; j < 8; j++) {
                float v = fmaf(a[j], normp[k0 + j], normp[128 + k0 + j]);
                a[j] = (v >= 0.f) ? v : 0.01f * v;
            }
        }
        short8 af;
#pragma unroll
        for (int j = 0; j < 8; j++) af[j] = (short)f2bf(a[j]);
#pragma unroll
        for (int nt = 0; nt < 8; nt++) {
            short8 bf = *(const short8*)(Wt + (size_t)(nt * 16 + m) * DD + k0);
            acc[nt] = __builtin_amdgcn_mfma_f32_16x16x32_bf16(af, bf, acc[nt], 0, 0, 0);
        }
    }

    // epilogue: repack through per-wave LDS tile (wave-internal, no barrier needed)
    float (*tile)[132] = lds[wslot];
#pragma unroll
    for (int nt = 0; nt < 8; nt++)
#pragma unroll
        for (int r = 0; r < 4; r++)
            tile[q * 4 + r][nt * 16 + m] = acc[nt][r];

    unsigned short* crow = C + (size_t)(wrow0 + m) * DD;
#pragma unroll
    for (int j = 0; j < 8; j++) {
        int col = q * 4 + 16 * j;
        float4 v = *(float4*)&tile[m][col];
        unsigned int lo = f2bf(v.x) | ((unsigned int)f2bf(v.y) << 16);
        unsigned int hi = f2bf(v.z) | ((unsigned int)f2bf(v.w) << 16);
        uint2 p; p.x = lo; p.y = hi;
        *(uint2*)(crow + col) = p;  // 8 B aligned
    }
}

// ---- CSR gather-aggregate + FUSED BN stats ----
// Block = 4 waves x 16 nodes. Lane owns feature pair (2l, 2l+1); accumulates
// sum/sumsq of the rounded-bf16 stored values; LDS reduce; 256 atomics/block.
__global__ __launch_bounds__(256) void gather_kernel(const unsigned short* __restrict__ xw,
                                                     const int* __restrict__ rowptr,
                                                     const int2* __restrict__ csr,
                                                     unsigned short* __restrict__ agg,
                                                     float* __restrict__ sums) {
    int w = threadIdx.x >> 6;
    int l = threadIdx.x & 63;
    int base = blockIdx.x * 64 + w * 16;
    float s0 = 0.f, q0 = 0.f, s1 = 0.f, q1 = 0.f;
    for (int j = 0; j < 16; j++) {
        int wid = base + j;
        if (wid >= NN) break;  // wave-uniform
        int beg = rowptr[wid], end = rowptr[wid + 1];
        float ax = 0.f, ay = 0.f;
        int i = beg;
        for (; i + 4 <= end; i += 4) {
            int2 r0 = csr[i], r1 = csr[i + 1], r2 = csr[i + 2], r3 = csr[i + 3];
            unsigned int u0 = *(const unsigned int*)(xw + (size_t)r0.x * DD + 2 * l);
            unsigned int u1 = *(const unsigned int*)(xw + (size_t)r1.x * DD + 2 * l);
            unsigned int u2 = *(const unsigned int*)(xw + (size_t)r2.x * DD + 2 * l);
            unsigned int u3 = *(const unsigned int*)(xw + (size_t)r3.x * DD + 2 * l);
            float c0 = __int_as_float(r0.y), c1 = __int_as_float(r1.y);
            float c2 = __int_as_float(r2.y), c3 = __int_as_float(r3.y);
            ax += bflo(u0) * c0 + bflo(u1) * c1 + bflo(u2) * c2 + bflo(u3) * c3;
            ay += bfhi(u0) * c0 + bfhi(u1) * c1 + bfhi(u2) * c2 + bfhi(u3) * c3;
        }
        for (; i < end; i++) {
            int2 r0 = csr[i];
            unsigned int u0 = *(const unsigned int*)(xw + (size_t)r0.x * DD + 2 * l);
            float c0 = __int_as_float(r0.y);
            ax += bflo(u0) * c0;
            ay += bfhi(u0) * c0;
        }
        unsigned int pa = (unsigned int)f2bf(ax) | ((unsigned int)f2bf(ay) << 16);
        ((unsigned int*)(agg + (size_t)wid * DD))[l] = pa;
        float rx = bflo(pa), ry = bfhi(pa);  // stats on stored (rounded) values
        s0 += rx; q0 += rx * rx;
        s1 += ry; q1 += ry * ry;
    }
    __shared__ float lds[4][64][4];
    lds[w][l][0] = s0; lds[w][l][1] = q0;
    lds[w][l][2] = s1; lds[w][l][3] = q1;
    __syncthreads();
    // thread t: feature-pair l2 = t&63, component jj = t>>6
    int l2 = threadIdx.x & 63, jj = threadIdx.x >> 6;
    float v = lds[0][l2][jj] + lds[1][l2][jj] + lds[2][l2][jj] + lds[3][l2][jj];
    // jj=0: sum(2l2); jj=1: sumsq(2l2); jj=2: sum(2l2+1); jj=3: sumsq(2l2+1)
    int addr = (jj & 1) * 128 + 2 * l2 + (jj >> 1);
    atomicAdd(&sums[addr], v);
}

// ---- fold sums -> scale/shift: scale=g*rsqrt(var+eps), shift=be-mu*scale ----
__global__ __launch_bounds__(128) void bnfin_kernel(const float* __restrict__ sums,
                                                    const float* __restrict__ g,
                                                    const float* __restrict__ be,
                                                    float* __restrict__ normp) {
    int d = threadIdx.x;
    const float invN = 1.0f / (float)NN;
    float mu = sums[d] * invN;
    float var = sums[128 + d] * invN - mu * mu;
    float sc = rsqrtf(var + 1e-5f) * g[d];
    normp[d] = sc;
    normp[128 + d] = be[d] - mu * sc;
}

// ---- final: out_fp32 = bf16(agg)*scale+shift (normp precomputed by bnfin) ----
__global__ __launch_bounds__(256) void bnapply_kernel(const unsigned short* __restrict__ h,
                                                      const float* __restrict__ normp,
                                                      float* __restrict__ out) {
    int idx = blockIdx.x * 256 + threadIdx.x;  // one per 4 elements
    if (idx >= NN * DD / 4) return;
    int d = (idx * 4) & 127;
    uint2 u = *(const uint2*)(h + idx * 4);
    float4 sc = *(const float4*)&normp[d];
    float4 sh = *(const float4*)&normp[128 + d];
    float4 o;
    o.x = fmaf(bflo(u.x), sc.x, sh.x);
    o.y = fmaf(bfhi(u.x), sc.y, sh.y);
    o.z = fmaf(bflo(u.y), sc.z, sh.z);
    o.w = fmaf(bfhi(u.y), sc.w, sh.w);
    *(float4*)&out[idx * 4] = o;
}

extern "C" void kernel_launch(void* const* d_in, const int* in_sizes, int n_in,
                              void* d_out, int out_size, void* d_ws, size_t ws_size,
                              hipStream_t stream) {
    const float* x = (const float*)d_in[0];
    const int* ei = (const int*)d_in[1];
    const int* srcp = ei;
    const int* dstp = ei + NE;
    const float* w[3]  = {(const float*)d_in[2], (const float*)d_in[6],  (const float*)d_in[10]};
    const float* g[3]  = {(const float*)d_in[4], (const float*)d_in[8],  (const float*)d_in[12]};
    const float* be[3] = {(const float*)d_in[5], (const float*)d_in[9],  (const float*)d_in[13]};

    // workspace layout (~43 MB), all chunks 16-B aligned
    unsigned short* xwb  = (unsigned short*)d_ws;        // bf16 xw  [NN*DD]
    unsigned short* aggb = xwb + (size_t)NN * DD;        // bf16 agg [NN*DD]
    int* deg    = (int*)(aggb + (size_t)NN * DD);        // [NN]
    int* cursor = deg + NN;                              // [NN]
    int* rowptr = cursor + NN;                           // [NN+16]
    float* dinv = (float*)(rowptr + NN + 16);            // [NN]
    float* sums = dinv + NN;                             // [3*256]
    float* ss   = sums + 3 * 256;                        // [3*256] scale/shift per layer
    int* partials = (int*)(ss + 3 * 256);                // [256]
    int* blockoff = partials + 256;                      // [256]
    unsigned short* Wt = (unsigned short*)(blockoff + 256);  // [3*128*128] bf16
    int2* csr = (int2*)(Wt + 3 * DD * DD);               // [NTOT] packed {src, coef}
    float* out = (float*)d_out;

    // ---- CSR build (once; edge_index constant across layers) ----
    hipMemsetAsync(deg, 0, 2 * NN * sizeof(int), stream);        // deg + cursor
    hipMemsetAsync(sums, 0, 3 * 256 * sizeof(float), stream);    // all layers' stats
    deg_kernel<<<(NE + 255) / 256, 256, 0, stream>>>(dstp, deg);
    scanA_kernel<<<NB, 256, 0, stream>>>(deg, partials, dinv);
    scanB_kernel<<<1, 256, 0, stream>>>(partials, blockoff, rowptr);
    scanC_kernel<<<NB, 256, 0, stream>>>(deg, blockoff, rowptr);
    fill_kernel<<<(NTOT + 255) / 256, 256, 0, stream>>>(srcp, dstp, rowptr, cursor, dinv, csr);
    wcvt_kernel<<<(3 * 64 * DD + 255) / 256, 256, 0, stream>>>(w[0], w[1], w[2], Wt);

    const int GEMM_GRID = (NN / 16 + 3) / 4;    // 938
    const int GATHER_GRID = (NN + 63) / 64;     // 938
    for (int L = 0; L < 3; ++L) {
        const float* normp = (L == 0) ? nullptr : (ss + (L - 1) * 256);
        if (L == 0)
            gemm_mfma_kernel<false><<<GEMM_GRID, 256, 0, stream>>>(x, Wt, normp, xwb);
        else
            gemm_mfma_kernel<true><<<GEMM_GRID, 256, 0, stream>>>(aggb, Wt + L * DD * DD, normp, xwb);
        gather_kernel<<<GATHER_GRID, 256, 0, stream>>>(xwb, rowptr, csr, aggb, sums + L * 256);
        bnfin_kernel<<<1, 128, 0, stream>>>(sums + L * 256, g[L], be[L], ss + L * 256);
        if (L == 2)
            bnapply_kernel<<<(NN * DD / 4 + 255) / 256, 256, 0, stream>>>(aggb, ss + L * 256, out);
    }
}